// Round 8
// baseline (1098.616 us; speedup 1.0000x reference)
//
#include <hip/hip_runtime.h>
#include <hip/hip_bf16.h>

#define N_SUB 100000
#define N_AGR 200000
#define N_URB 100000
#define E_SS  1600000
#define E_AS  400000
#define E_US  200000
#define E_TOT 2200000
#define HID   128
#define DHRU  32
#define NOUT  16
#define NL    3
#define SCAN_T 12500  // N_SUB / 8

typedef unsigned short u16;
typedef unsigned int u32;
typedef long long i64;
typedef short bf16x8 __attribute__((ext_vector_type(8)));
typedef float f32x4 __attribute__((ext_vector_type(4)));

#define FIXS 4294967296.0f   // 2^32
#define FIXR 2.3283064365386963e-10f  // 2^-32

static __device__ __forceinline__ u16 f2b(float f) {
    u32 x = __float_as_uint(f);
    u32 r = (x + 0x7fffu + ((x >> 16) & 1u)) >> 16;  // RNE
    return (u16)r;
}
static __device__ __forceinline__ float blo(u32 u) { return __uint_as_float(u << 16); }
static __device__ __forceinline__ float bhi(u32 u) { return __uint_as_float(u & 0xffff0000u); }
// order-independent exact accumulation term: fp32 -> fixed-point int64 (trunc, deterministic)
static __device__ __forceinline__ i64 fx(float v) { return (i64)(v * FIXS); }

// ---------------- CSR build ----------------

__global__ void hist3_kernel(const int* __restrict__ ss_dst, const int* __restrict__ as_dst,
                             const int* __restrict__ us_dst, int* __restrict__ deg_ss,
                             int* __restrict__ deg_as, int* __restrict__ deg_us) {
    int i = blockIdx.x * 256 + threadIdx.x;
    if (i < E_SS) atomicAdd(&deg_ss[ss_dst[i]], 1);
    else if (i < E_SS + E_AS) atomicAdd(&deg_as[as_dst[i - E_SS]], 1);
    else if (i < E_TOT) atomicAdd(&deg_us[us_dst[i - E_SS - E_AS]], 1);
}

__global__ void scan_p1(const int* __restrict__ deg, int* __restrict__ tsum) {
    int i = blockIdx.x * 256 + threadIdx.x;
    if (i >= 3 * SCAN_T) return;
    const int4* p = (const int4*)(deg + i * 8);
    int4 a = p[0], b = p[1];
    tsum[i] = a.x + a.y + a.z + a.w + b.x + b.y + b.z + b.w;
}

__global__ void scan_p2(int* __restrict__ tsum_all) {
    __shared__ int sh[256];
    int* tsum = tsum_all + blockIdx.x * SCAN_T;
    const int tid = threadIdx.x;
    const int start = tid * 49;
    const int end = min(start + 49, SCAN_T);
    int s = 0;
    for (int i = start; i < end; ++i) s += tsum[i];
    sh[tid] = s;
    __syncthreads();
    for (int o = 1; o < 256; o <<= 1) {
        int t = (tid >= o) ? sh[tid - o] : 0;
        __syncthreads();
        sh[tid] += t;
        __syncthreads();
    }
    int off = (tid > 0) ? sh[tid - 1] : 0;
    for (int i = start; i < end; ++i) {
        int v = tsum[i];
        tsum[i] = off;
        off += v;
    }
}

__global__ void scan_p3(int* __restrict__ degcur, const int* __restrict__ tsum,
                        int* __restrict__ ro_ss, int* __restrict__ ro_as,
                        int* __restrict__ ro_us, float* __restrict__ inv_deg) {
    int i = blockIdx.x * 256 + threadIdx.x;
    if (i >= 3 * SCAN_T) return;
    int seg = i / SCAN_T, li = i - seg * SCAN_T;
    int* ro = (seg == 0) ? ro_ss : (seg == 1) ? ro_as : ro_us;
    int off = tsum[i];
#pragma unroll
    for (int j = 0; j < 8; ++j) {
        int gidx = i * 8 + j;
        int idx = li * 8 + j;
        int d = degcur[gidx];
        ro[idx] = off;
        if (seg == 0) inv_deg[idx] = 1.0f / (float)(d > 1 ? d : 1);
        degcur[gidx] = off;
        off += d;
    }
    if (li == SCAN_T - 1) ro[N_SUB] = off;
}

__global__ void fill3_kernel(const int* __restrict__ ss_src, const int* __restrict__ ss_dst,
                             const int* __restrict__ as_src, const int* __restrict__ as_dst,
                             const int* __restrict__ us_src, const int* __restrict__ us_dst,
                             int* __restrict__ cur_ss, int* __restrict__ cur_as,
                             int* __restrict__ cur_us, int* __restrict__ csr_ss,
                             int* __restrict__ csr_as, int* __restrict__ csr_us) {
    int i = blockIdx.x * 256 + threadIdx.x;
    const int* src; const int* dst; int* cur; int* csr; int e;
    if (i < E_SS)               { src = ss_src; dst = ss_dst; cur = cur_ss; csr = csr_ss; e = i; }
    else if (i < E_SS + E_AS)   { src = as_src; dst = as_dst; cur = cur_as; csr = csr_as; e = i - E_SS; }
    else if (i < E_TOT)         { src = us_src; dst = us_dst; cur = cur_us; csr = csr_us; e = i - E_SS - E_AS; }
    else return;
    int p = atomicAdd(&cur[dst[e]], 1);
    csr[p] = src[e];
}

// canonicalize segment order (locality + determinism belt-and-braces).
// fixed 64 rounds of odd-even transposition -- always sufficient for len<=64.
__global__ __launch_bounds__(256)
void sort_csr3(const int* __restrict__ ro_ss, int* __restrict__ csr_ss,
               const int* __restrict__ ro_as, int* __restrict__ csr_as,
               const int* __restrict__ ro_us, int* __restrict__ csr_us) {
    __shared__ int buf[4][64];
    int gnode = blockIdx.x * 4 + (threadIdx.x >> 6);
    int lane = threadIdx.x & 63;
    int w = threadIdx.x >> 6;
    int seg = gnode / N_SUB;
    int node = gnode - seg * N_SUB;
    const int* ro = (seg == 0) ? ro_ss : (seg == 1) ? ro_as : ro_us;
    int* csr = (seg == 0) ? csr_ss : (seg == 1) ? csr_as : csr_us;
    int beg = ro[node];
    int len = ro[node + 1] - beg;
    int nload = min(len, 64);
    buf[w][lane] = (lane < nload) ? csr[beg + lane] : 0x7FFFFFFF;
    for (int r = 0; r < 64; ++r) {
        __syncthreads();
        if (lane < 32) {
            int idx = 2 * lane + (r & 1);
            if (idx + 1 < 64) {
                int a = buf[w][idx], b = buf[w][idx + 1];
                if (b < a) { buf[w][idx] = b; buf[w][idx + 1] = a; }
            }
        }
    }
    __syncthreads();
    if (lane < nload) csr[beg + lane] = buf[w][lane];
}

// ---------------- hru aggregation: CSR gather, int64 exact accum, bf16 out ----------------
__global__ __launch_bounds__(256)
void agg2_gather(const float* __restrict__ x_agr, const float* __restrict__ x_urb,
                 const int* __restrict__ ro_as, const int* __restrict__ csr_as,
                 const int* __restrict__ ro_us, const int* __restrict__ csr_us,
                 u16* __restrict__ agg2b, int n) {
    int node = blockIdx.x * 4 + (threadIdx.x >> 6);
    int lane = threadIdx.x & 63;
    if (node >= n) return;
    const bool is_us = lane >= 32;
    const int col = lane & 31;
    const int* ro = is_us ? ro_us : ro_as;
    const int* csr = is_us ? csr_us : csr_as;
    const float* x = is_us ? x_urb : x_agr;
    int beg = ro[node], end = ro[node + 1];
    i64 acc = 0;
    for (int p = beg; p < end; ++p) {
        acc += fx(x[(size_t)csr[p] * 32 + col]);
    }
    agg2b[(size_t)node * 64 + lane] = f2b((float)acc * FIXR);
}

// ---------------- weight prep ----------------
__global__ void add3_kernel(const float* __restrict__ a, const float* __restrict__ b,
                            const float* __restrict__ c, float* __restrict__ o, int n) {
    int i = blockIdx.x * 256 + threadIdx.x;
    if (i < n) o[i] = a[i] + b[i] + c[i];
}

__global__ void build_bp(const float* __restrict__ Wl_ss, const float* __restrict__ Wr_ss,
                         const float* __restrict__ Wr_as, const float* __restrict__ Wr_us,
                         const float* __restrict__ Wl_as, const float* __restrict__ Wl_us,
                         u16* __restrict__ Bp) {
    int b = blockIdx.x;           // 3*10*8 = 240
    int lane = threadIdx.x;       // 64
    int lay = b / 80, rem = b % 80, s = rem / 8, c = rem % 8;
    int col = c * 16 + (lane & 15);
    u16* o = Bp + (size_t)(((lay * 80) + s * 8 + c) * 64 + lane) * 8;
#pragma unroll
    for (int j = 0; j < 8; ++j) {
        int k = s * 32 + (lane >> 4) * 8 + j;
        float v;
        if (k < 128) {
            v = Wl_ss[((size_t)lay * 128 + k) * 128 + col];
        } else if (k < 256) {
            size_t idx = ((size_t)lay * 128 + (k - 128)) * 128 + col;
            v = Wr_ss[idx] + Wr_as[idx] + Wr_us[idx];
        } else if (k < 288) {
            v = Wl_as[((size_t)lay * 32 + (k - 256)) * 128 + col];
        } else {
            v = Wl_us[((size_t)lay * 32 + (k - 288)) * 128 + col];
        }
        o[j] = f2b(v);
    }
}

// ---------------- fp32 -> bf16 convert ----------------
__global__ void cvt_f32_bf16(const float* __restrict__ in, u16* __restrict__ o, int n4) {
    int i = blockIdx.x * 256 + threadIdx.x;
    if (i >= n4) return;
    float4 v = ((const float4*)in)[i];
    ushort4 u;
    u.x = f2b(v.x); u.y = f2b(v.y); u.z = f2b(v.z); u.w = f2b(v.w);
    ((ushort4*)o)[i] = u;
}

// ---------------- per-layer CSR gather aggregation (int64 exact accum) ----------------
// one wave per node; 4 lane-groups of 16 each gather a different edge's row with
// dwordx4 loads; int64 fixed-point accumulation => bitwise independent of edge order.
__global__ __launch_bounds__(256)
void agg_ss_bf16(const u16* __restrict__ h, const int* __restrict__ ro,
                 const int* __restrict__ csr, const float* __restrict__ inv_deg,
                 u16* __restrict__ out, int n, int use_mean) {
    int node = blockIdx.x * 4 + (threadIdx.x >> 6);
    if (node >= n) return;
    int lane = threadIdx.x & 63;
    int g = lane >> 4, t = lane & 15;
    int beg = ro[node], end = ro[node + 1];
    i64 acc[8] = {0, 0, 0, 0, 0, 0, 0, 0};
    int p = beg;
    for (; p + 3 < end; p += 4) {
        int s = csr[p + g];
        uint4 q = *(const uint4*)(h + (size_t)s * 128 + t * 8);
        acc[0] += fx(blo(q.x)); acc[1] += fx(bhi(q.x));
        acc[2] += fx(blo(q.y)); acc[3] += fx(bhi(q.y));
        acc[4] += fx(blo(q.z)); acc[5] += fx(bhi(q.z));
        acc[6] += fx(blo(q.w)); acc[7] += fx(bhi(q.w));
    }
    int rem = end - p;
    if (g < rem) {
        int s = csr[p + g];
        uint4 q = *(const uint4*)(h + (size_t)s * 128 + t * 8);
        acc[0] += fx(blo(q.x)); acc[1] += fx(bhi(q.x));
        acc[2] += fx(blo(q.y)); acc[3] += fx(bhi(q.y));
        acc[4] += fx(blo(q.z)); acc[5] += fx(bhi(q.z));
        acc[6] += fx(blo(q.w)); acc[7] += fx(bhi(q.w));
    }
#pragma unroll
    for (int j = 0; j < 8; ++j) {
        acc[j] += __shfl_xor(acc[j], 16, 64);
        acc[j] += __shfl_xor(acc[j], 32, 64);
    }
    if (g == 0) {
        float v[8];
        float iv = use_mean ? inv_deg[node] : 1.0f;
#pragma unroll
        for (int j = 0; j < 8; ++j) v[j] = (float)acc[j] * FIXR * iv;
        uint4 o;
        o.x = (u32)f2b(v[0]) | ((u32)f2b(v[1]) << 16);
        o.y = (u32)f2b(v[2]) | ((u32)f2b(v[3]) << 16);
        o.z = (u32)f2b(v[4]) | ((u32)f2b(v[5]) << 16);
        o.w = (u32)f2b(v[6]) | ((u32)f2b(v[7]) << 16);
        *(uint4*)(out + (size_t)node * 128 + t * 8) = o;
    }
}

// ---------------- fused layer GEMM via MFMA bf16 (R5-proven form) ----------------
__global__ __launch_bounds__(256)
void layer_gemm_mfma(const u16* __restrict__ agss, const u16* __restrict__ h,
                     const u16* __restrict__ agg2b, const u16* __restrict__ Bp,
                     const float* __restrict__ bsum, u16* __restrict__ out, int n) {
    __shared__ __align__(16) u16 tile[4][32][136];
    const int tid = threadIdx.x;
    const int w = tid >> 6, l = tid & 63;
    const int lr = l & 15, lq = l >> 4;
    const int rows0 = blockIdx.x * 128 + w * 32;

    f32x4 acc[2][8];
#pragma unroll
    for (int rf = 0; rf < 2; ++rf)
#pragma unroll
        for (int c = 0; c < 8; ++c) acc[rf][c] = (f32x4){0.f, 0.f, 0.f, 0.f};

    const bf16x8 zf = {0, 0, 0, 0, 0, 0, 0, 0};

#pragma unroll
    for (int s = 0; s < 10; ++s) {
        const u16* X;
        int ld, koff;
        if (s < 4)      { X = agss;  ld = 128; koff = s * 32 + lq * 8; }
        else if (s < 8) { X = h;     ld = 128; koff = (s - 4) * 32 + lq * 8; }
        else            { X = agg2b; ld = 64;  koff = (s - 8) * 32 + lq * 8; }
        bf16x8 a[2];
#pragma unroll
        for (int rf = 0; rf < 2; ++rf) {
            int row = rows0 + rf * 16 + lr;
            a[rf] = (row < n) ? *(const bf16x8*)(X + (size_t)row * ld + koff) : zf;
        }
        const u16* bp = Bp + ((size_t)(s * 8) * 64 + l) * 8;
#pragma unroll
        for (int c = 0; c < 8; ++c) {
            bf16x8 b = *(const bf16x8*)(bp + (size_t)c * 64 * 8);
            acc[0][c] = __builtin_amdgcn_mfma_f32_16x16x32_bf16(a[0], b, acc[0][c], 0, 0, 0);
            acc[1][c] = __builtin_amdgcn_mfma_f32_16x16x32_bf16(a[1], b, acc[1][c], 0, 0, 0);
        }
    }

    float bias[8];
#pragma unroll
    for (int c = 0; c < 8; ++c) bias[c] = bsum[c * 16 + lr];

#pragma unroll
    for (int rf = 0; rf < 2; ++rf)
#pragma unroll
        for (int c = 0; c < 8; ++c)
#pragma unroll
            for (int r = 0; r < 4; ++r) {
                float v = fmaxf(acc[rf][c][r] + bias[c], 0.f);
                tile[w][rf * 16 + lq * 4 + r][c * 16 + lr] = f2b(v);
            }

#pragma unroll
    for (int i = 0; i < 8; ++i) {
        int row = i * 4 + lq;
        int grow = rows0 + row;
        if (grow < n)
            *(bf16x8*)(out + (size_t)grow * 128 + lr * 8) =
                *(const bf16x8*)&tile[w][row][lr * 8];
    }
}

// ---------------- final projection + softmax (R5-proven form) ----------------
__global__ __launch_bounds__(256)
void final_kernel(const u32* __restrict__ h32, const float* __restrict__ Wf,
                  const float* __restrict__ bfv, float* __restrict__ out, int n) {
    __shared__ float wsh[HID * NOUT + NOUT];
    for (int i = threadIdx.x; i < HID * NOUT; i += 256) wsh[i] = Wf[i];
    if (threadIdx.x < NOUT) wsh[HID * NOUT + threadIdx.x] = bfv[threadIdx.x];
    __syncthreads();
    int t = blockIdx.x * 256 + threadIdx.x;
    int node = t >> 4, c = t & 15;
    if (node >= n) return;
    const u32* hr = h32 + (size_t)node * 64;
    float acc = wsh[HID * NOUT + c];
#pragma unroll 4
    for (int k2 = 0; k2 < 64; ++k2) {
        u32 u = hr[k2];
        acc += blo(u) * wsh[(2 * k2) * NOUT + c] + bhi(u) * wsh[(2 * k2 + 1) * NOUT + c];
    }
    float m = acc;
#pragma unroll
    for (int o = 8; o >= 1; o >>= 1) m = fmaxf(m, __shfl_xor(m, o, 16));
    float e = expf(acc - m);
    float ssum = e;
#pragma unroll
    for (int o = 8; o >= 1; o >>= 1) ssum += __shfl_xor(ssum, o, 16);
    out[(size_t)node * NOUT + c] = e / ssum;
}

extern "C" void kernel_launch(void* const* d_in, const int* in_sizes, int n_in,
                              void* d_out, int out_size, void* d_ws, size_t ws_size,
                              hipStream_t stream) {
    const float* x_sub = (const float*)d_in[0];
    const float* x_agr = (const float*)d_in[1];
    const float* x_urb = (const float*)d_in[2];
    const int* ss_src = (const int*)d_in[3];
    const int* ss_dst = (const int*)d_in[4];
    const int* as_src = (const int*)d_in[5];
    const int* as_dst = (const int*)d_in[6];
    const int* us_src = (const int*)d_in[7];
    const int* us_dst = (const int*)d_in[8];
    const float* Wl_ss = (const float*)d_in[9];
    const float* bl_ss = (const float*)d_in[10];
    const float* Wr_ss = (const float*)d_in[11];
    const float* Wl_as = (const float*)d_in[12];
    const float* bl_as = (const float*)d_in[13];
    const float* Wr_as = (const float*)d_in[14];
    const float* Wl_us = (const float*)d_in[15];
    const float* bl_us = (const float*)d_in[16];
    const float* Wr_us = (const float*)d_in[17];
    const float* Wf = (const float*)d_in[18];
    const float* bfv = (const float*)d_in[19];
    float* out = (float*)d_out;

    char* ws = (char*)d_ws;
    u16* h0      = (u16*)(ws + 0);             // 25,600,000
    u16* hA      = (u16*)(ws + 25600000);      // 25,600,000
    u16* hB      = (u16*)(ws + 51200000);      // 25,600,000
    u16* agss    = (u16*)(ws + 76800000);      // 25,600,000
    u16* agg2b   = (u16*)(ws + 102400000);     // 12,800,000
    float* inv_deg = (float*)(ws + 115200000); //    400,000
    int* ro_ss   = (int*)(ws + 115600000);     //    400,016
    int* ro_as   = (int*)(ws + 116000016);     //    400,016
    int* ro_us   = (int*)(ws + 116400032);     //    400,016
    int* deg_ss  = (int*)(ws + 116800048);     //    400,000  } contiguous:
    int* deg_as  = (int*)(ws + 117200048);     //    400,000  } one memset,
    int* deg_us  = (int*)(ws + 117600048);     //    400,000  } one scan
    int* csr_ss  = (int*)(ws + 118000048);     //  6,400,000
    int* csr_as  = (int*)(ws + 124400048);     //  1,600,000
    int* csr_us  = (int*)(ws + 126000048);     //    800,000
    int* tsum    = (int*)(ws + 126800048);     //    150,000 (3*SCAN_T)
    u16* Bp      = (u16*)(ws + 126950048);     //    245,760
    float* b_sum = (float*)(ws + 127195808);   //      1,536

    // ---- CSR build for all 3 edge types ----
    hipMemsetAsync(deg_ss, 0, 3 * N_SUB * sizeof(int), stream);
    hist3_kernel<<<(E_TOT + 255) / 256, 256, 0, stream>>>(ss_dst, as_dst, us_dst,
                                                          deg_ss, deg_as, deg_us);
    scan_p1<<<(3 * SCAN_T + 255) / 256, 256, 0, stream>>>(deg_ss, tsum);
    scan_p2<<<3, 256, 0, stream>>>(tsum);
    scan_p3<<<(3 * SCAN_T + 255) / 256, 256, 0, stream>>>(deg_ss, tsum, ro_ss, ro_as,
                                                          ro_us, inv_deg);
    fill3_kernel<<<(E_TOT + 255) / 256, 256, 0, stream>>>(ss_src, ss_dst, as_src, as_dst,
                                                          us_src, us_dst, deg_ss, deg_as,
                                                          deg_us, csr_ss, csr_as, csr_us);
    sort_csr3<<<(3 * N_SUB) / 4, 256, 0, stream>>>(ro_ss, csr_ss, ro_as, csr_as,
                                                   ro_us, csr_us);

    // ---- layer-invariant hru aggregation ----
    agg2_gather<<<(N_SUB + 3) / 4, 256, 0, stream>>>(x_agr, x_urb, ro_as, csr_as,
                                                     ro_us, csr_us, agg2b, N_SUB);

    // ---- weight packing + bias sums ----
    build_bp<<<240, 64, 0, stream>>>(Wl_ss, Wr_ss, Wr_as, Wr_us, Wl_as, Wl_us, Bp);
    add3_kernel<<<2, 256, 0, stream>>>(bl_ss, bl_as, bl_us, b_sum, NL * HID);

    // ---- x_sub -> bf16 ----
    cvt_f32_bf16<<<(N_SUB * HID / 4 + 255) / 256, 256, 0, stream>>>(x_sub, h0, N_SUB * HID / 4);

    const int agg_grid = (N_SUB + 3) / 4;
    const int gemm_grid = (N_SUB + 127) / 128;
    const size_t BPL = 40960;  // Bp per-layer stride (u16)

    // ---- layer 0: sum aggregation ----
    agg_ss_bf16<<<agg_grid, 256, 0, stream>>>(h0, ro_ss, csr_ss, inv_deg, agss, N_SUB, 0);
    layer_gemm_mfma<<<gemm_grid, 256, 0, stream>>>(agss, h0, agg2b, Bp + 0 * BPL,
                                                   b_sum + 0 * HID, hA, N_SUB);

    // ---- layer 1: mean aggregation ----
    agg_ss_bf16<<<agg_grid, 256, 0, stream>>>(hA, ro_ss, csr_ss, inv_deg, agss, N_SUB, 1);
    layer_gemm_mfma<<<gemm_grid, 256, 0, stream>>>(agss, hA, agg2b, Bp + 1 * BPL,
                                                   b_sum + 1 * HID, hB, N_SUB);

    // ---- layer 2: mean aggregation ----
    agg_ss_bf16<<<agg_grid, 256, 0, stream>>>(hB, ro_ss, csr_ss, inv_deg, agss, N_SUB, 1);
    layer_gemm_mfma<<<gemm_grid, 256, 0, stream>>>(agss, hB, agg2b, Bp + 2 * BPL,
                                                   b_sum + 2 * HID, hA, N_SUB);

    // ---- final projection + softmax ----
    final_kernel<<<(N_SUB * NOUT + 255) / 256, 256, 0, stream>>>((const u32*)hA, Wf, bfv,
                                                                 out, N_SUB);
}

// Round 9
// 799.703 us; speedup vs baseline: 1.3738x; 1.3738x over previous
//
#include <hip/hip_runtime.h>
#include <hip/hip_bf16.h>

#define N_SUB 100000
#define N_AGR 200000
#define N_URB 100000
#define E_SS  1600000
#define E_AS  400000
#define E_US  200000
#define E_TOT 2200000
#define HID   128
#define DHRU  32
#define NOUT  16
#define NL    3
#define SCAN_T 12500  // N_SUB / 8

typedef unsigned short u16;
typedef unsigned int u32;
typedef long long i64;
typedef short bf16x8 __attribute__((ext_vector_type(8)));
typedef float f32x4 __attribute__((ext_vector_type(4)));

#define FIXS 4294967296.0f   // 2^32
#define FIXR 2.3283064365386963e-10f  // 2^-32

static __device__ __forceinline__ u16 f2b(float f) {
    u32 x = __float_as_uint(f);
    u32 r = (x + 0x7fffu + ((x >> 16) & 1u)) >> 16;  // RNE
    return (u16)r;
}
static __device__ __forceinline__ float blo(u32 u) { return __uint_as_float(u << 16); }
static __device__ __forceinline__ float bhi(u32 u) { return __uint_as_float(u & 0xffff0000u); }
// order-independent exact accumulation term: fp32 -> fixed-point int64 (trunc, deterministic)
static __device__ __forceinline__ i64 fx(float v) { return (i64)(v * FIXS); }

// ---------------- CSR build ----------------

__global__ void hist3_kernel(const int* __restrict__ ss_dst, const int* __restrict__ as_dst,
                             const int* __restrict__ us_dst, int* __restrict__ deg_ss,
                             int* __restrict__ deg_as, int* __restrict__ deg_us) {
    int i = blockIdx.x * 256 + threadIdx.x;
    if (i < E_SS) atomicAdd(&deg_ss[ss_dst[i]], 1);
    else if (i < E_SS + E_AS) atomicAdd(&deg_as[as_dst[i - E_SS]], 1);
    else if (i < E_TOT) atomicAdd(&deg_us[us_dst[i - E_SS - E_AS]], 1);
}

__global__ void scan_p1(const int* __restrict__ deg, int* __restrict__ tsum) {
    int i = blockIdx.x * 256 + threadIdx.x;
    if (i >= 3 * SCAN_T) return;
    const int4* p = (const int4*)(deg + i * 8);
    int4 a = p[0], b = p[1];
    tsum[i] = a.x + a.y + a.z + a.w + b.x + b.y + b.z + b.w;
}

__global__ void scan_p2(int* __restrict__ tsum_all) {
    __shared__ int sh[256];
    int* tsum = tsum_all + blockIdx.x * SCAN_T;
    const int tid = threadIdx.x;
    const int start = tid * 49;
    const int end = min(start + 49, SCAN_T);
    int s = 0;
    for (int i = start; i < end; ++i) s += tsum[i];
    sh[tid] = s;
    __syncthreads();
    for (int o = 1; o < 256; o <<= 1) {
        int t = (tid >= o) ? sh[tid - o] : 0;
        __syncthreads();
        sh[tid] += t;
        __syncthreads();
    }
    int off = (tid > 0) ? sh[tid - 1] : 0;
    for (int i = start; i < end; ++i) {
        int v = tsum[i];
        tsum[i] = off;
        off += v;
    }
}

__global__ void scan_p3(int* __restrict__ degcur, const int* __restrict__ tsum,
                        int* __restrict__ ro_ss, int* __restrict__ ro_as,
                        int* __restrict__ ro_us, float* __restrict__ inv_deg) {
    int i = blockIdx.x * 256 + threadIdx.x;
    if (i >= 3 * SCAN_T) return;
    int seg = i / SCAN_T, li = i - seg * SCAN_T;
    int* ro = (seg == 0) ? ro_ss : (seg == 1) ? ro_as : ro_us;
    int off = tsum[i];
#pragma unroll
    for (int j = 0; j < 8; ++j) {
        int gidx = i * 8 + j;
        int idx = li * 8 + j;
        int d = degcur[gidx];
        ro[idx] = off;
        if (seg == 0) inv_deg[idx] = 1.0f / (float)(d > 1 ? d : 1);
        degcur[gidx] = off;
        off += d;
    }
    if (li == SCAN_T - 1) ro[N_SUB] = off;
}

// fill order per segment is nondeterministic (atomic cursor), but harmless:
// every consumer does an order-independent int64 fixed-point sum over the
// segment multiset, which hist+scan fix deterministically.
__global__ void fill3_kernel(const int* __restrict__ ss_src, const int* __restrict__ ss_dst,
                             const int* __restrict__ as_src, const int* __restrict__ as_dst,
                             const int* __restrict__ us_src, const int* __restrict__ us_dst,
                             int* __restrict__ cur_ss, int* __restrict__ cur_as,
                             int* __restrict__ cur_us, int* __restrict__ csr_ss,
                             int* __restrict__ csr_as, int* __restrict__ csr_us) {
    int i = blockIdx.x * 256 + threadIdx.x;
    const int* src; const int* dst; int* cur; int* csr; int e;
    if (i < E_SS)               { src = ss_src; dst = ss_dst; cur = cur_ss; csr = csr_ss; e = i; }
    else if (i < E_SS + E_AS)   { src = as_src; dst = as_dst; cur = cur_as; csr = csr_as; e = i - E_SS; }
    else if (i < E_TOT)         { src = us_src; dst = us_dst; cur = cur_us; csr = csr_us; e = i - E_SS - E_AS; }
    else return;
    int p = atomicAdd(&cur[dst[e]], 1);
    csr[p] = src[e];
}

// ---------------- hru aggregation: CSR gather, int64 exact accum, bf16 out ----------------
__global__ __launch_bounds__(256)
void agg2_gather(const float* __restrict__ x_agr, const float* __restrict__ x_urb,
                 const int* __restrict__ ro_as, const int* __restrict__ csr_as,
                 const int* __restrict__ ro_us, const int* __restrict__ csr_us,
                 u16* __restrict__ agg2b, int n) {
    int node = blockIdx.x * 4 + (threadIdx.x >> 6);
    int lane = threadIdx.x & 63;
    if (node >= n) return;
    const bool is_us = lane >= 32;
    const int col = lane & 31;
    const int* ro = is_us ? ro_us : ro_as;
    const int* csr = is_us ? csr_us : csr_as;
    const float* x = is_us ? x_urb : x_agr;
    int beg = ro[node], end = ro[node + 1];
    i64 acc = 0;
    for (int p = beg; p < end; ++p) {
        acc += fx(x[(size_t)csr[p] * 32 + col]);
    }
    agg2b[(size_t)node * 64 + lane] = f2b((float)acc * FIXR);
}

// ---------------- weight prep ----------------
__global__ void add3_kernel(const float* __restrict__ a, const float* __restrict__ b,
                            const float* __restrict__ c, float* __restrict__ o, int n) {
    int i = blockIdx.x * 256 + threadIdx.x;
    if (i < n) o[i] = a[i] + b[i] + c[i];
}

__global__ void build_bp(const float* __restrict__ Wl_ss, const float* __restrict__ Wr_ss,
                         const float* __restrict__ Wr_as, const float* __restrict__ Wr_us,
                         const float* __restrict__ Wl_as, const float* __restrict__ Wl_us,
                         u16* __restrict__ Bp) {
    int b = blockIdx.x;           // 3*10*8 = 240
    int lane = threadIdx.x;       // 64
    int lay = b / 80, rem = b % 80, s = rem / 8, c = rem % 8;
    int col = c * 16 + (lane & 15);
    u16* o = Bp + (size_t)(((lay * 80) + s * 8 + c) * 64 + lane) * 8;
#pragma unroll
    for (int j = 0; j < 8; ++j) {
        int k = s * 32 + (lane >> 4) * 8 + j;
        float v;
        if (k < 128) {
            v = Wl_ss[((size_t)lay * 128 + k) * 128 + col];
        } else if (k < 256) {
            size_t idx = ((size_t)lay * 128 + (k - 128)) * 128 + col;
            v = Wr_ss[idx] + Wr_as[idx] + Wr_us[idx];
        } else if (k < 288) {
            v = Wl_as[((size_t)lay * 32 + (k - 256)) * 128 + col];
        } else {
            v = Wl_us[((size_t)lay * 32 + (k - 288)) * 128 + col];
        }
        o[j] = f2b(v);
    }
}

// ---------------- fp32 -> bf16 convert ----------------
__global__ void cvt_f32_bf16(const float* __restrict__ in, u16* __restrict__ o, int n4) {
    int i = blockIdx.x * 256 + threadIdx.x;
    if (i >= n4) return;
    float4 v = ((const float4*)in)[i];
    ushort4 u;
    u.x = f2b(v.x); u.y = f2b(v.y); u.z = f2b(v.z); u.w = f2b(v.w);
    ((ushort4*)o)[i] = u;
}

// ---------------- per-layer CSR gather aggregation (int64 exact accum) ----------------
// one wave per node; 4 lane-groups of 16 each gather a different edge's row with
// dwordx4 loads; int64 fixed-point accumulation => bitwise independent of edge order.
__global__ __launch_bounds__(256)
void agg_ss_bf16(const u16* __restrict__ h, const int* __restrict__ ro,
                 const int* __restrict__ csr, const float* __restrict__ inv_deg,
                 u16* __restrict__ out, int n, int use_mean) {
    int node = blockIdx.x * 4 + (threadIdx.x >> 6);
    if (node >= n) return;
    int lane = threadIdx.x & 63;
    int g = lane >> 4, t = lane & 15;
    int beg = ro[node], end = ro[node + 1];
    i64 acc[8] = {0, 0, 0, 0, 0, 0, 0, 0};
    int p = beg;
    for (; p + 3 < end; p += 4) {
        int s = csr[p + g];
        uint4 q = *(const uint4*)(h + (size_t)s * 128 + t * 8);
        acc[0] += fx(blo(q.x)); acc[1] += fx(bhi(q.x));
        acc[2] += fx(blo(q.y)); acc[3] += fx(bhi(q.y));
        acc[4] += fx(blo(q.z)); acc[5] += fx(bhi(q.z));
        acc[6] += fx(blo(q.w)); acc[7] += fx(bhi(q.w));
    }
    int rem = end - p;
    if (g < rem) {
        int s = csr[p + g];
        uint4 q = *(const uint4*)(h + (size_t)s * 128 + t * 8);
        acc[0] += fx(blo(q.x)); acc[1] += fx(bhi(q.x));
        acc[2] += fx(blo(q.y)); acc[3] += fx(bhi(q.y));
        acc[4] += fx(blo(q.z)); acc[5] += fx(bhi(q.z));
        acc[6] += fx(blo(q.w)); acc[7] += fx(bhi(q.w));
    }
#pragma unroll
    for (int j = 0; j < 8; ++j) {
        acc[j] += __shfl_xor(acc[j], 16, 64);
        acc[j] += __shfl_xor(acc[j], 32, 64);
    }
    if (g == 0) {
        float v[8];
        float iv = use_mean ? inv_deg[node] : 1.0f;
#pragma unroll
        for (int j = 0; j < 8; ++j) v[j] = (float)acc[j] * FIXR * iv;
        uint4 o;
        o.x = (u32)f2b(v[0]) | ((u32)f2b(v[1]) << 16);
        o.y = (u32)f2b(v[2]) | ((u32)f2b(v[3]) << 16);
        o.z = (u32)f2b(v[4]) | ((u32)f2b(v[5]) << 16);
        o.w = (u32)f2b(v[6]) | ((u32)f2b(v[7]) << 16);
        *(uint4*)(out + (size_t)node * 128 + t * 8) = o;
    }
}

// ---------------- fused layer GEMM via MFMA bf16 ----------------
__global__ __launch_bounds__(256)
void layer_gemm_mfma(const u16* __restrict__ agss, const u16* __restrict__ h,
                     const u16* __restrict__ agg2b, const u16* __restrict__ Bp,
                     const float* __restrict__ bsum, u16* __restrict__ out, int n) {
    __shared__ __align__(16) u16 tile[4][32][136];
    const int tid = threadIdx.x;
    const int w = tid >> 6, l = tid & 63;
    const int lr = l & 15, lq = l >> 4;
    const int rows0 = blockIdx.x * 128 + w * 32;

    f32x4 acc[2][8];
#pragma unroll
    for (int rf = 0; rf < 2; ++rf)
#pragma unroll
        for (int c = 0; c < 8; ++c) acc[rf][c] = (f32x4){0.f, 0.f, 0.f, 0.f};

    const bf16x8 zf = {0, 0, 0, 0, 0, 0, 0, 0};

#pragma unroll
    for (int s = 0; s < 10; ++s) {
        const u16* X;
        int ld, koff;
        if (s < 4)      { X = agss;  ld = 128; koff = s * 32 + lq * 8; }
        else if (s < 8) { X = h;     ld = 128; koff = (s - 4) * 32 + lq * 8; }
        else            { X = agg2b; ld = 64;  koff = (s - 8) * 32 + lq * 8; }
        bf16x8 a[2];
#pragma unroll
        for (int rf = 0; rf < 2; ++rf) {
            int row = rows0 + rf * 16 + lr;
            a[rf] = (row < n) ? *(const bf16x8*)(X + (size_t)row * ld + koff) : zf;
        }
        const u16* bp = Bp + ((size_t)(s * 8) * 64 + l) * 8;
#pragma unroll
        for (int c = 0; c < 8; ++c) {
            bf16x8 b = *(const bf16x8*)(bp + (size_t)c * 64 * 8);
            acc[0][c] = __builtin_amdgcn_mfma_f32_16x16x32_bf16(a[0], b, acc[0][c], 0, 0, 0);
            acc[1][c] = __builtin_amdgcn_mfma_f32_16x16x32_bf16(a[1], b, acc[1][c], 0, 0, 0);
        }
    }

    float bias[8];
#pragma unroll
    for (int c = 0; c < 8; ++c) bias[c] = bsum[c * 16 + lr];

#pragma unroll
    for (int rf = 0; rf < 2; ++rf)
#pragma unroll
        for (int c = 0; c < 8; ++c)
#pragma unroll
            for (int r = 0; r < 4; ++r) {
                float v = fmaxf(acc[rf][c][r] + bias[c], 0.f);
                tile[w][rf * 16 + lq * 4 + r][c * 16 + lr] = f2b(v);
            }

#pragma unroll
    for (int i = 0; i < 8; ++i) {
        int row = i * 4 + lq;
        int grow = rows0 + row;
        if (grow < n)
            *(bf16x8*)(out + (size_t)grow * 128 + lr * 8) =
                *(const bf16x8*)&tile[w][row][lr * 8];
    }
}

// ---------------- final projection + softmax ----------------
__global__ __launch_bounds__(256)
void final_kernel(const u32* __restrict__ h32, const float* __restrict__ Wf,
                  const float* __restrict__ bfv, float* __restrict__ out, int n) {
    __shared__ float wsh[HID * NOUT + NOUT];
    for (int i = threadIdx.x; i < HID * NOUT; i += 256) wsh[i] = Wf[i];
    if (threadIdx.x < NOUT) wsh[HID * NOUT + threadIdx.x] = bfv[threadIdx.x];
    __syncthreads();
    int t = blockIdx.x * 256 + threadIdx.x;
    int node = t >> 4, c = t & 15;
    if (node >= n) return;
    const u32* hr = h32 + (size_t)node * 64;
    float acc = wsh[HID * NOUT + c];
#pragma unroll 4
    for (int k2 = 0; k2 < 64; ++k2) {
        u32 u = hr[k2];
        acc += blo(u) * wsh[(2 * k2) * NOUT + c] + bhi(u) * wsh[(2 * k2 + 1) * NOUT + c];
    }
    float m = acc;
#pragma unroll
    for (int o = 8; o >= 1; o >>= 1) m = fmaxf(m, __shfl_xor(m, o, 16));
    float e = expf(acc - m);
    float ssum = e;
#pragma unroll
    for (int o = 8; o >= 1; o >>= 1) ssum += __shfl_xor(ssum, o, 16);
    out[(size_t)node * NOUT + c] = e / ssum;
}

extern "C" void kernel_launch(void* const* d_in, const int* in_sizes, int n_in,
                              void* d_out, int out_size, void* d_ws, size_t ws_size,
                              hipStream_t stream) {
    const float* x_sub = (const float*)d_in[0];
    const float* x_agr = (const float*)d_in[1];
    const float* x_urb = (const float*)d_in[2];
    const int* ss_src = (const int*)d_in[3];
    const int* ss_dst = (const int*)d_in[4];
    const int* as_src = (const int*)d_in[5];
    const int* as_dst = (const int*)d_in[6];
    const int* us_src = (const int*)d_in[7];
    const int* us_dst = (const int*)d_in[8];
    const float* Wl_ss = (const float*)d_in[9];
    const float* bl_ss = (const float*)d_in[10];
    const float* Wr_ss = (const float*)d_in[11];
    const float* Wl_as = (const float*)d_in[12];
    const float* bl_as = (const float*)d_in[13];
    const float* Wr_as = (const float*)d_in[14];
    const float* Wl_us = (const float*)d_in[15];
    const float* bl_us = (const float*)d_in[16];
    const float* Wr_us = (const float*)d_in[17];
    const float* Wf = (const float*)d_in[18];
    const float* bfv = (const float*)d_in[19];
    float* out = (float*)d_out;

    char* ws = (char*)d_ws;
    u16* h0      = (u16*)(ws + 0);             // 25,600,000
    u16* hA      = (u16*)(ws + 25600000);      // 25,600,000
    u16* hB      = (u16*)(ws + 51200000);      // 25,600,000
    u16* agss    = (u16*)(ws + 76800000);      // 25,600,000
    u16* agg2b   = (u16*)(ws + 102400000);     // 12,800,000
    float* inv_deg = (float*)(ws + 115200000); //    400,000
    int* ro_ss   = (int*)(ws + 115600000);     //    400,016
    int* ro_as   = (int*)(ws + 116000016);     //    400,016
    int* ro_us   = (int*)(ws + 116400032);     //    400,016
    int* deg_ss  = (int*)(ws + 116800048);     //    400,000  } contiguous:
    int* deg_as  = (int*)(ws + 117200048);     //    400,000  } one memset,
    int* deg_us  = (int*)(ws + 117600048);     //    400,000  } one scan
    int* csr_ss  = (int*)(ws + 118000048);     //  6,400,000
    int* csr_as  = (int*)(ws + 124400048);     //  1,600,000
    int* csr_us  = (int*)(ws + 126000048);     //    800,000
    int* tsum    = (int*)(ws + 126800048);     //    150,000 (3*SCAN_T)
    u16* Bp      = (u16*)(ws + 126950048);     //    245,760
    float* b_sum = (float*)(ws + 127195808);   //      1,536

    // ---- CSR build for all 3 edge types ----
    hipMemsetAsync(deg_ss, 0, 3 * N_SUB * sizeof(int), stream);
    hist3_kernel<<<(E_TOT + 255) / 256, 256, 0, stream>>>(ss_dst, as_dst, us_dst,
                                                          deg_ss, deg_as, deg_us);
    scan_p1<<<(3 * SCAN_T + 255) / 256, 256, 0, stream>>>(deg_ss, tsum);
    scan_p2<<<3, 256, 0, stream>>>(tsum);
    scan_p3<<<(3 * SCAN_T + 255) / 256, 256, 0, stream>>>(deg_ss, tsum, ro_ss, ro_as,
                                                          ro_us, inv_deg);
    fill3_kernel<<<(E_TOT + 255) / 256, 256, 0, stream>>>(ss_src, ss_dst, as_src, as_dst,
                                                          us_src, us_dst, deg_ss, deg_as,
                                                          deg_us, csr_ss, csr_as, csr_us);

    // ---- layer-invariant hru aggregation ----
    agg2_gather<<<(N_SUB + 3) / 4, 256, 0, stream>>>(x_agr, x_urb, ro_as, csr_as,
                                                     ro_us, csr_us, agg2b, N_SUB);

    // ---- weight packing + bias sums ----
    build_bp<<<240, 64, 0, stream>>>(Wl_ss, Wr_ss, Wr_as, Wr_us, Wl_as, Wl_us, Bp);
    add3_kernel<<<2, 256, 0, stream>>>(bl_ss, bl_as, bl_us, b_sum, NL * HID);

    // ---- x_sub -> bf16 ----
    cvt_f32_bf16<<<(N_SUB * HID / 4 + 255) / 256, 256, 0, stream>>>(x_sub, h0, N_SUB * HID / 4);

    const int agg_grid = (N_SUB + 3) / 4;
    const int gemm_grid = (N_SUB + 127) / 128;
    const size_t BPL = 40960;  // Bp per-layer stride (u16)

    // ---- layer 0: sum aggregation ----
    agg_ss_bf16<<<agg_grid, 256, 0, stream>>>(h0, ro_ss, csr_ss, inv_deg, agss, N_SUB, 0);
    layer_gemm_mfma<<<gemm_grid, 256, 0, stream>>>(agss, h0, agg2b, Bp + 0 * BPL,
                                                   b_sum + 0 * HID, hA, N_SUB);

    // ---- layer 1: mean aggregation ----
    agg_ss_bf16<<<agg_grid, 256, 0, stream>>>(hA, ro_ss, csr_ss, inv_deg, agss, N_SUB, 1);
    layer_gemm_mfma<<<gemm_grid, 256, 0, stream>>>(agss, hA, agg2b, Bp + 1 * BPL,
                                                   b_sum + 1 * HID, hB, N_SUB);

    // ---- layer 2: mean aggregation ----
    agg_ss_bf16<<<agg_grid, 256, 0, stream>>>(hB, ro_ss, csr_ss, inv_deg, agss, N_SUB, 1);
    layer_gemm_mfma<<<gemm_grid, 256, 0, stream>>>(agss, hB, agg2b, Bp + 2 * BPL,
                                                   b_sum + 2 * HID, hA, N_SUB);

    // ---- final projection + softmax ----
    final_kernel<<<(N_SUB * NOUT + 255) / 256, 256, 0, stream>>>((const u32*)hA, Wf, bfv,
                                                                 out, N_SUB);
}